// Round 16
// baseline (211.696 us; speedup 1.0000x reference)
//
#include <hip/hip_runtime.h>
#include <hip/hip_bf16.h>

// SNN: B=2048, NI=1024, NH=2048, NO=10, T=128, BETA=0.95, THR=1.0
// K1: cur1 = x @ w1^T + b1 via bf16x3 MFMA (frozen).
// K2 r16 — register diet to kill spill/remat bloat (r15: live ~205 regs vs
// 128 cap -> 5x VALU issue): (1) single-bf16 w2 (drop blo, -32 regs, half
// MFMA); (2) prev-spike extracted from Wprev bits (drop cc/c1m/spk arrays,
// -96 regs; 6 inst/neuron-step); (3) r15 pipeline skeleton unchanged.

#define B_   2048
#define NI_  1024
#define NH_  2048
#define NO_  10
#define T_   128
#define GB_  8
#define NBLK (B_ / GB_)   // 256 blocks = 1/CU
#define TC_  16
#define NCH  (T_ / TC_)   // 8 chunks

typedef __attribute__((ext_vector_type(8))) short short8;
typedef __attribute__((ext_vector_type(4))) float f32x4;
typedef __attribute__((ext_vector_type(4))) unsigned int u32x4;

// bf16 round-to-nearest-even of an f32, low 16 bits.
__device__ __forceinline__ unsigned int bf16_rne(float f) {
  unsigned int u = __float_as_uint(f);
  return (u + 0x7FFFu + ((u >> 16) & 1u)) >> 16;
}

// ---------------- Kernel 1: cur1 = x @ w1^T + b1 (bf16x3 MFMA) --------------
#define G_ASTRIDE 144
#define G_AOFF    0
#define G_BOFF    (128 * G_ASTRIDE)
#define G_SMEM    (2 * 128 * G_ASTRIDE)

__global__ __launch_bounds__(512, 2) void gemm_cur1(
    const float* __restrict__ x, const float* __restrict__ w1,
    const float* __restrict__ b1, float* __restrict__ cur1) {
  __shared__ __align__(16) char smem[G_SMEM];
  const int tid = threadIdx.x;
  const int lane = tid & 63;
  const int wv = tid >> 6;
  const int wm = wv >> 2;
  const int wn = wv & 3;
  const int n15 = lane & 15;
  const int g = lane >> 4;
  const int brow = blockIdx.y * 128;
  const int bcol = blockIdx.x * 128;

  const int r_st = tid >> 3;
  const int kq = tid & 7;

  f32x4 acc[4][2];
#pragma unroll
  for (int tm = 0; tm < 4; ++tm)
#pragma unroll
    for (int tn = 0; tn < 2; ++tn) acc[tm][tn] = f32x4{0, 0, 0, 0};

  for (int kt = 0; kt < NI_; kt += 32) {
#pragma unroll
    for (int p = 0; p < 2; ++p) {
      const int r = r_st + p * 64;
      const float4 va = *reinterpret_cast<const float4*>(
          &x[(size_t)(brow + r) * NI_ + kt + kq * 4]);
      const float4 vb = *reinterpret_cast<const float4*>(
          &w1[(size_t)(bcol + r) * NI_ + kt + kq * 4]);
      const float fa[4] = {va.x, va.y, va.z, va.w};
      const float fb[4] = {vb.x, vb.y, vb.z, vb.w};
      unsigned ha[4], la[4], hb[4], lb[4];
#pragma unroll
      for (int c = 0; c < 4; ++c) {
        ha[c] = bf16_rne(fa[c]);
        la[c] = bf16_rne(fa[c] - __uint_as_float(ha[c] << 16));
        hb[c] = bf16_rne(fb[c]);
        lb[c] = bf16_rne(fb[c] - __uint_as_float(hb[c] << 16));
      }
      char* arow = smem + G_AOFF + r * G_ASTRIDE;
      char* brw  = smem + G_BOFF + r * G_ASTRIDE;
      *reinterpret_cast<uint2*>(arow + kq * 8) =
          uint2{ha[0] | (ha[1] << 16), ha[2] | (ha[3] << 16)};
      *reinterpret_cast<uint2*>(arow + 64 + kq * 8) =
          uint2{la[0] | (la[1] << 16), la[2] | (la[3] << 16)};
      *reinterpret_cast<uint2*>(brw + kq * 8) =
          uint2{hb[0] | (hb[1] << 16), hb[2] | (hb[3] << 16)};
      *reinterpret_cast<uint2*>(brw + 64 + kq * 8) =
          uint2{lb[0] | (lb[1] << 16), lb[2] | (lb[3] << 16)};
    }
    __syncthreads();

    short8 ah[4], al[4], bh2[2], bl2[2];
#pragma unroll
    for (int tm = 0; tm < 4; ++tm) {
      const char* p = smem + G_AOFF + (wm * 64 + tm * 16 + n15) * G_ASTRIDE;
      ah[tm] = *reinterpret_cast<const short8*>(p + g * 16);
      al[tm] = *reinterpret_cast<const short8*>(p + 64 + g * 16);
    }
#pragma unroll
    for (int tn = 0; tn < 2; ++tn) {
      const char* p = smem + G_BOFF + (wn * 32 + tn * 16 + n15) * G_ASTRIDE;
      bh2[tn] = *reinterpret_cast<const short8*>(p + g * 16);
      bl2[tn] = *reinterpret_cast<const short8*>(p + 64 + g * 16);
    }
#pragma unroll
    for (int tm = 0; tm < 4; ++tm)
#pragma unroll
      for (int tn = 0; tn < 2; ++tn) {
        acc[tm][tn] = __builtin_amdgcn_mfma_f32_16x16x32_bf16(
            ah[tm], bh2[tn], acc[tm][tn], 0, 0, 0);
        acc[tm][tn] = __builtin_amdgcn_mfma_f32_16x16x32_bf16(
            ah[tm], bl2[tn], acc[tm][tn], 0, 0, 0);
        acc[tm][tn] = __builtin_amdgcn_mfma_f32_16x16x32_bf16(
            al[tm], bh2[tn], acc[tm][tn], 0, 0, 0);
      }
    __syncthreads();
  }

#pragma unroll
  for (int tn = 0; tn < 2; ++tn) {
    const int col = bcol + wn * 32 + tn * 16 + n15;
    const float bias = b1[col];
#pragma unroll
    for (int tm = 0; tm < 4; ++tm) {
      const int rowb = brow + wm * 64 + tm * 16 + g * 4;
#pragma unroll
      for (int r = 0; r < 4; ++r)
        cur1[(size_t)(rowb + r) * NH_ + col] = acc[tm][tn][r] + bias;
    }
  }
}

// ---------------- Kernel 2: pipelined LIF + time-as-M MFMA ------------------
// LDS map (bytes):
//   lut  uint2[16]                      at 0       (128; 32 words = 32 banks)
//   bits u32[2 par][8 b][16 tl][65]     at 128     (2 x 33280)
//   comb f32[2 par][8 w][8 b][4 g][40]  at 66688   (2 x 40960)
#define LUT_OFF  0
#define BITS_OFF 128
#define BITS_PAR 8320    // words per parity
#define COMB_OFF 66688
#define COMB_PAR 10240   // floats per parity
#define SMEM_BYTES 148608

__global__ __launch_bounds__(512, 2) void snn_loop(
    const float* __restrict__ cur1, const float* __restrict__ w2,
    const float* __restrict__ b2, float* __restrict__ spk2_rec,
    float* __restrict__ mem2_rec) {
  extern __shared__ char smem[];
  uint2* lutw = reinterpret_cast<uint2*>(smem + LUT_OFF);
  const uint2* lut = lutw;
  unsigned* bits = reinterpret_cast<unsigned*>(smem + BITS_OFF);
  float* comb = reinterpret_cast<float*>(smem + COMB_OFF);
  const int tid = threadIdx.x;
  const int lane = tid & 63;
  const int w = tid >> 6;               // wave id = local batch id
  const int bbase = blockIdx.x * GB_;
  const int bb = bbase + w;

  if (tid < 16) {
    lutw[tid] = uint2{(tid & 1 ? 0x3F80u : 0u) | (tid & 2 ? 0x3F800000u : 0u),
                      (tid & 4 ? 0x3F80u : 0u) | (tid & 8 ? 0x3F800000u : 0u)};
  }

  // ---- layer-1 state: mem1 + c1v ONLY (64 regs). Prev spike lives in the
  //      Wprev bit register; reset folded as cc = c1v - (float)bit.
  float mem1[32], c1v[32];
  unsigned Wprev = 0;
  {
    const float* base = cur1 + (size_t)bb * NH_ + lane * 32;
#pragma unroll
    for (int q = 0; q < 8; ++q) {
      const float4 v = *reinterpret_cast<const float4*>(base + q * 4);
      c1v[q * 4 + 0] = v.x; c1v[q * 4 + 1] = v.y;
      c1v[q * 4 + 2] = v.z; c1v[q * 4 + 3] = v.w;
    }
#pragma unroll
    for (int i = 0; i < 32; ++i) mem1[i] = 0.0f;
  }

  // ---- w2 B-fragments in registers — single bf16 (hi only) ----
  u32x4 bhi[8];
  {
    const int o = lane & 15;
    const int koff = (lane >> 4) * 8;
#pragma unroll
    for (int kbl = 0; kbl < 8; ++kbl) {
      const int kb = w * 8 + kbl;
      unsigned int hw[4];
#pragma unroll
      for (int p = 0; p < 4; ++p) {
        unsigned int h0 = 0, h1 = 0;
        if (o < NO_) {
          const int k = kb * 32 + koff + p * 2;
          h0 = bf16_rne(w2[(size_t)o * NH_ + k]);
          h1 = bf16_rne(w2[(size_t)o * NH_ + k + 1]);
        }
        hw[p] = h0 | (h1 << 16);
      }
      bhi[kbl] = u32x4{hw[0], hw[1], hw[2], hw[3]};
    }
  }

  // ---- layer-2 state: lanes < NO_ of wave w own (batch bb, output o) ----
  float mem2 = 0.0f, spk2 = 0.0f, b2v = 0.0f;
  float *srec = nullptr, *mrec = nullptr;
  if (lane < NO_) {
    b2v = b2[lane];
    srec = spk2_rec + (size_t)bb * NO_ + lane;
    mrec = mem2_rec + (size_t)bb * NO_ + lane;
  }

  const int n15 = lane & 15;
  const int g = lane >> 4;
  const unsigned char* bytes = reinterpret_cast<const unsigned char*>(smem);

  // ---- P1 macro: one LIF step tl into parity-p bits.
  // Per neuron: bfe, cvt, sub, fma, cmp, addc = 6 inst, zero array overhead.
  auto P1_STEP = [&](unsigned* bitsP, int tl) {
    unsigned W = 0;
#pragma unroll
    for (int i = 31; i >= 0; --i) {
      const float s = (float)((Wprev >> i) & 1u);
      const float m = fmaf(0.95f, mem1[i], c1v[i] - s);
      mem1[i] = m;
      W = W + W + (m > 1.0f ? 1u : 0u);
    }
    Wprev = W;
    bitsP[(w * TC_ + tl) * 65 + lane] = W;
  };

  // ---- prologue: P1(chunk 0) -> parity 0 ----
  for (int tl = 0; tl < TC_; ++tl) P1_STEP(bits, tl);
  __syncthreads();

  for (int ch = 0; ch < NCH; ++ch) {
    const int cur = ch & 1;
    unsigned* bitsN = bits + (cur ^ 1) * BITS_PAR;
    float* combC = comb + cur * COMB_PAR;
    const float* combV = comb + (cur ^ 1) * COMB_PAR;  // parity of ch-1
    const int bbyte = BITS_OFF + cur * (BITS_PAR * 4);

    // ---- (a) P3/4 for chunk ch-1 (independent of (b)) ----
    if (ch > 0 && lane < NO_) {
      const float* cbase = combV + w * 160 + lane * 4;
#pragma unroll
      for (int tl = 0; tl < TC_; ++tl) {
        const int off = (tl >> 2) * 40 + (tl & 3);
        float s = 0.0f;
#pragma unroll
        for (int ww = 0; ww < 8; ++ww) s += cbase[ww * 1280 + off];
        const float cur2 = s + b2v;
        float m = fmaf(0.95f, mem2, cur2);
        m = m - spk2;
        mem2 = m;
        spk2 = (m > 1.0f) ? 1.0f : 0.0f;
        const int t = (ch - 1) * TC_ + tl;
        srec[(size_t)t * (B_ * NO_)] = spk2;
        mrec[(size_t)t * (B_ * NO_)] = m;
      }
    }

    // ---- (b) fused P2(ch) + P1(ch+1): 8 b-iters x {8 MFMA | 2 LIF steps} --
#pragma unroll
    for (int b = 0; b < GB_; ++b) {
      const int rbase = bbyte + ((b * TC_ + n15) * 65 + w * 8) * 4 + g;
      f32x4 acc = {0.0f, 0.0f, 0.0f, 0.0f};
#pragma unroll
      for (int kbl = 0; kbl < 8; ++kbl) {
        const unsigned byt = bytes[rbase + kbl * 4];
        const uint2 lo2 = lut[byt & 15u];
        const uint2 hi2 = lut[byt >> 4];
        const u32x4 A = {lo2.x, lo2.y, hi2.x, hi2.y};
        const short8 af = __builtin_bit_cast(short8, A);
        acc = __builtin_amdgcn_mfma_f32_16x16x32_bf16(
            af, __builtin_bit_cast(short8, bhi[kbl]), acc, 0, 0, 0);
      }
      if (n15 < NO_)
        *reinterpret_cast<f32x4*>(
            &combC[w * 1280 + b * 160 + g * 40 + n15 * 4]) = acc;
      if (ch < NCH - 1) {
        P1_STEP(bitsN, 2 * b);
        P1_STEP(bitsN, 2 * b + 1);
      }
    }

    __syncthreads();
    // fences: bits(nxt) ready for P2(ch+1); comb(cur) ready for P3/4(ch);
    // all reads of bits(cur) done before P1(ch+2) overwrites it; all reads
    // of comb(ch-1 parity) done before P2(ch+1) overwrites it.
  }

  // ---- epilogue: P3/4 for last chunk (parity (NCH-1)&1) ----
  if (lane < NO_) {
    const float* cbase = comb + ((NCH - 1) & 1) * COMB_PAR + w * 160 + lane * 4;
#pragma unroll
    for (int tl = 0; tl < TC_; ++tl) {
      const int off = (tl >> 2) * 40 + (tl & 3);
      float s = 0.0f;
#pragma unroll
      for (int ww = 0; ww < 8; ++ww) s += cbase[ww * 1280 + off];
      const float cur2 = s + b2v;
      float m = fmaf(0.95f, mem2, cur2);
      m = m - spk2;
      mem2 = m;
      spk2 = (m > 1.0f) ? 1.0f : 0.0f;
      const int t = (NCH - 1) * TC_ + tl;
      srec[(size_t)t * (B_ * NO_)] = spk2;
      mrec[(size_t)t * (B_ * NO_)] = m;
    }
  }
}

// ---------------------------------------------------------------------------
extern "C" void kernel_launch(void* const* d_in, const int* in_sizes, int n_in,
                              void* d_out, int out_size, void* d_ws, size_t ws_size,
                              hipStream_t stream) {
  const float* x  = (const float*)d_in[0];
  const float* w1 = (const float*)d_in[1];
  const float* b1 = (const float*)d_in[2];
  const float* w2 = (const float*)d_in[3];
  const float* b2 = (const float*)d_in[4];
  float* out = (float*)d_out;
  float* cur1 = (float*)d_ws;

  float* spk2_rec = out;
  float* mem2_rec = out + (size_t)T_ * B_ * NO_;

  (void)hipFuncSetAttribute(reinterpret_cast<const void*>(snn_loop),
                            hipFuncAttributeMaxDynamicSharedMemorySize,
                            SMEM_BYTES);

  dim3 g1(NH_ / 128, B_ / 128);
  gemm_cur1<<<g1, 512, 0, stream>>>(x, w1, b1, cur1);
  snn_loop<<<NBLK, 512, SMEM_BYTES, stream>>>(cur1, w2, b2, spk2_rec, mem2_rec);
}

// Round 17
// 184.272 us; speedup vs baseline: 1.1488x; 1.1488x over previous
//
#include <hip/hip_runtime.h>
#include <hip/hip_bf16.h>

// SNN: B=2048, NI=1024, NH=2048, NO=10, T=128, BETA=0.95, THR=1.0
// K1: cur1 = x @ w1^T + b1 via bf16x3 MFMA (frozen).
// K2 r17 — 16 waves in ONE 1024-thread block per CU (4 waves/SIMD without
// co-residency): P1 half-batch/wave (16 neurons/lane, 4-inst cc-form),
// P2 (kc,bset)-split with single-bf16 w2, P3/4 on waves 0-7. r15 pipeline
// skeleton (TC=16, dbuf bits+comb, 1 barrier/bundle) unchanged.

#define B_   2048
#define NI_  1024
#define NH_  2048
#define NO_  10
#define T_   128
#define GB_  8
#define NBLK (B_ / GB_)   // 256 blocks = 1/CU
#define TC_  16
#define NCH  (T_ / TC_)   // 8 chunks

typedef __attribute__((ext_vector_type(8))) short short8;
typedef __attribute__((ext_vector_type(4))) float f32x4;
typedef __attribute__((ext_vector_type(4))) unsigned int u32x4;

// bf16 round-to-nearest-even of an f32, low 16 bits.
__device__ __forceinline__ unsigned int bf16_rne(float f) {
  unsigned int u = __float_as_uint(f);
  return (u + 0x7FFFu + ((u >> 16) & 1u)) >> 16;
}

// ---------------- Kernel 1: cur1 = x @ w1^T + b1 (bf16x3 MFMA) --------------
#define G_ASTRIDE 144
#define G_AOFF    0
#define G_BOFF    (128 * G_ASTRIDE)
#define G_SMEM    (2 * 128 * G_ASTRIDE)

__global__ __launch_bounds__(512, 2) void gemm_cur1(
    const float* __restrict__ x, const float* __restrict__ w1,
    const float* __restrict__ b1, float* __restrict__ cur1) {
  __shared__ __align__(16) char smem[G_SMEM];
  const int tid = threadIdx.x;
  const int lane = tid & 63;
  const int wv = tid >> 6;
  const int wm = wv >> 2;
  const int wn = wv & 3;
  const int n15 = lane & 15;
  const int g = lane >> 4;
  const int brow = blockIdx.y * 128;
  const int bcol = blockIdx.x * 128;

  const int r_st = tid >> 3;
  const int kq = tid & 7;

  f32x4 acc[4][2];
#pragma unroll
  for (int tm = 0; tm < 4; ++tm)
#pragma unroll
    for (int tn = 0; tn < 2; ++tn) acc[tm][tn] = f32x4{0, 0, 0, 0};

  for (int kt = 0; kt < NI_; kt += 32) {
#pragma unroll
    for (int p = 0; p < 2; ++p) {
      const int r = r_st + p * 64;
      const float4 va = *reinterpret_cast<const float4*>(
          &x[(size_t)(brow + r) * NI_ + kt + kq * 4]);
      const float4 vb = *reinterpret_cast<const float4*>(
          &w1[(size_t)(bcol + r) * NI_ + kt + kq * 4]);
      const float fa[4] = {va.x, va.y, va.z, va.w};
      const float fb[4] = {vb.x, vb.y, vb.z, vb.w};
      unsigned ha[4], la[4], hb[4], lb[4];
#pragma unroll
      for (int c = 0; c < 4; ++c) {
        ha[c] = bf16_rne(fa[c]);
        la[c] = bf16_rne(fa[c] - __uint_as_float(ha[c] << 16));
        hb[c] = bf16_rne(fb[c]);
        lb[c] = bf16_rne(fb[c] - __uint_as_float(hb[c] << 16));
      }
      char* arow = smem + G_AOFF + r * G_ASTRIDE;
      char* brw  = smem + G_BOFF + r * G_ASTRIDE;
      *reinterpret_cast<uint2*>(arow + kq * 8) =
          uint2{ha[0] | (ha[1] << 16), ha[2] | (ha[3] << 16)};
      *reinterpret_cast<uint2*>(arow + 64 + kq * 8) =
          uint2{la[0] | (la[1] << 16), la[2] | (la[3] << 16)};
      *reinterpret_cast<uint2*>(brw + kq * 8) =
          uint2{hb[0] | (hb[1] << 16), hb[2] | (hb[3] << 16)};
      *reinterpret_cast<uint2*>(brw + 64 + kq * 8) =
          uint2{lb[0] | (lb[1] << 16), lb[2] | (lb[3] << 16)};
    }
    __syncthreads();

    short8 ah[4], al[4], bh2[2], bl2[2];
#pragma unroll
    for (int tm = 0; tm < 4; ++tm) {
      const char* p = smem + G_AOFF + (wm * 64 + tm * 16 + n15) * G_ASTRIDE;
      ah[tm] = *reinterpret_cast<const short8*>(p + g * 16);
      al[tm] = *reinterpret_cast<const short8*>(p + 64 + g * 16);
    }
#pragma unroll
    for (int tn = 0; tn < 2; ++tn) {
      const char* p = smem + G_BOFF + (wn * 32 + tn * 16 + n15) * G_ASTRIDE;
      bh2[tn] = *reinterpret_cast<const short8*>(p + g * 16);
      bl2[tn] = *reinterpret_cast<const short8*>(p + 64 + g * 16);
    }
#pragma unroll
    for (int tm = 0; tm < 4; ++tm)
#pragma unroll
      for (int tn = 0; tn < 2; ++tn) {
        acc[tm][tn] = __builtin_amdgcn_mfma_f32_16x16x32_bf16(
            ah[tm], bh2[tn], acc[tm][tn], 0, 0, 0);
        acc[tm][tn] = __builtin_amdgcn_mfma_f32_16x16x32_bf16(
            ah[tm], bl2[tn], acc[tm][tn], 0, 0, 0);
        acc[tm][tn] = __builtin_amdgcn_mfma_f32_16x16x32_bf16(
            al[tm], bh2[tn], acc[tm][tn], 0, 0, 0);
      }
    __syncthreads();
  }

#pragma unroll
  for (int tn = 0; tn < 2; ++tn) {
    const int col = bcol + wn * 32 + tn * 16 + n15;
    const float bias = b1[col];
#pragma unroll
    for (int tm = 0; tm < 4; ++tm) {
      const int rowb = brow + wm * 64 + tm * 16 + g * 4;
#pragma unroll
      for (int r = 0; r < 4; ++r)
        cur1[(size_t)(rowb + r) * NH_ + col] = acc[tm][tn][r] + bias;
    }
  }
}

// ---------------- Kernel 2: 16-wave pipelined LIF + time-as-M MFMA ----------
// Wave roles: P1: bq=w&7, hf=w>>3 (16 neurons/lane, h=hf*1024+lane*16+i).
//             P2: kc=w>>1 (K-chunk of 256), bset=w&1 (batches bset*4..+3).
//             P3/4: waves 0-7, batch w, lanes<10.
// LDS map (bytes):
//   lut  uint2[16]                      at 0       (128)
//   bits u32[2 par][8 b][16 tl][65]     at 128     (2 x 33280)
//   comb f32[2 par][8 kc][8 b][4 g][40] at 66688   (2 x 40960)
#define LUT_OFF  0
#define BITS_OFF 128
#define BITS_PAR 8320    // words per parity
#define COMB_OFF 66688
#define COMB_PAR 10240   // floats per parity
#define SMEM_BYTES 148608

__global__ __launch_bounds__(1024, 1) void snn_loop(
    const float* __restrict__ cur1, const float* __restrict__ w2,
    const float* __restrict__ b2, float* __restrict__ spk2_rec,
    float* __restrict__ mem2_rec) {
  extern __shared__ char smem[];
  uint2* lutw = reinterpret_cast<uint2*>(smem + LUT_OFF);
  const uint2* lut = lutw;
  float* comb = reinterpret_cast<float*>(smem + COMB_OFF);
  const int tid = threadIdx.x;
  const int lane = tid & 63;
  const int w = tid >> 6;               // wave 0..15
  const int bq = w & 7;                 // P1: local batch
  const int hf = w >> 3;                // P1: neuron half
  const int kc = w >> 1;                // P2: K-chunk (0..7)
  const int bset = w & 1;               // P2: batch set (4 batches)
  const int bbase = blockIdx.x * GB_;

  if (tid < 16) {
    lutw[tid] = uint2{(tid & 1 ? 0x3F80u : 0u) | (tid & 2 ? 0x3F800000u : 0u),
                      (tid & 4 ? 0x3F80u : 0u) | (tid & 8 ? 0x3F800000u : 0u)};
  }

  // ---- P1 state: 16 neurons/lane, r15 4-inst cc-form (64 regs) ----
  float mem1[16], c1v[16], c1m[16], cc[16];
  {
    const float* base = cur1 + (size_t)(bbase + bq) * NH_ + hf * 1024 + lane * 16;
#pragma unroll
    for (int q = 0; q < 4; ++q) {
      const float4 v = *reinterpret_cast<const float4*>(base + q * 4);
      c1v[q * 4 + 0] = v.x; c1v[q * 4 + 1] = v.y;
      c1v[q * 4 + 2] = v.z; c1v[q * 4 + 3] = v.w;
    }
#pragma unroll
    for (int i = 0; i < 16; ++i) {
      mem1[i] = 0.0f;
      c1m[i] = c1v[i] - 1.0f;
      cc[i] = c1v[i];
    }
  }

  // ---- P2: w2 B-fragments, single bf16 (32 regs); kb = kc*8 + kbl ----
  u32x4 bhi[8];
  {
    const int o = lane & 15;
    const int koff = (lane >> 4) * 8;
#pragma unroll
    for (int kbl = 0; kbl < 8; ++kbl) {
      const int kb = kc * 8 + kbl;
      unsigned int hw[4];
#pragma unroll
      for (int p = 0; p < 4; ++p) {
        unsigned int h0 = 0, h1 = 0;
        if (o < NO_) {
          const int k = kb * 32 + koff + p * 2;
          h0 = bf16_rne(w2[(size_t)o * NH_ + k]);
          h1 = bf16_rne(w2[(size_t)o * NH_ + k + 1]);
        }
        hw[p] = h0 | (h1 << 16);
      }
      bhi[kbl] = u32x4{hw[0], hw[1], hw[2], hw[3]};
    }
  }

  // ---- layer-2 state: waves 0-7, lanes < NO_ own (batch w, output lane) ----
  float mem2 = 0.0f, spk2 = 0.0f, b2v = 0.0f;
  float *srec = nullptr, *mrec = nullptr;
  if (w < 8 && lane < NO_) {
    b2v = b2[lane];
    srec = spk2_rec + (size_t)(bbase + w) * NO_ + lane;
    mrec = mem2_rec + (size_t)(bbase + w) * NO_ + lane;
  }

  const int n15 = lane & 15;
  const int g = lane >> 4;
  const unsigned char* bytes = reinterpret_cast<const unsigned char*>(smem);

  // P1 halfword slot: word (bq*TC+tl)*65 + hf*32 + (lane>>1), half lane&1
  const int bits_hw = (hf * 32 + (lane >> 1)) * 2 + (lane & 1);

  auto P1_STEP = [&](unsigned short* bitsP16, int tl) {
    unsigned W = 0;
#pragma unroll
    for (int i = 15; i >= 0; --i) {
      const float m = fmaf(0.95f, mem1[i], cc[i]);
      mem1[i] = m;
      const bool c = m > 1.0f;
      W = W + W + (c ? 1u : 0u);
      cc[i] = c ? c1m[i] : c1v[i];
    }
    bitsP16[(bq * TC_ + tl) * 130 + bits_hw] = (unsigned short)W;
  };

  // ---- prologue: P1(chunk 0) -> parity 0 ----
  {
    unsigned short* b16 = reinterpret_cast<unsigned short*>(smem + BITS_OFF);
    for (int tl = 0; tl < TC_; ++tl) P1_STEP(b16, tl);
  }
  __syncthreads();

  for (int ch = 0; ch < NCH; ++ch) {
    const int cur = ch & 1;
    unsigned short* bitsN16 = reinterpret_cast<unsigned short*>(
        smem + BITS_OFF + (cur ^ 1) * (BITS_PAR * 4));
    float* combC = comb + cur * COMB_PAR;
    const float* combV = comb + (cur ^ 1) * COMB_PAR;  // parity of ch-1
    const int bbyte = BITS_OFF + cur * (BITS_PAR * 4);

    // ---- (a) P3/4 for chunk ch-1 (waves 0-7) ----
    if (ch > 0 && w < 8 && lane < NO_) {
      const float* cbase = combV + w * 160 + lane * 4;
#pragma unroll
      for (int tl = 0; tl < TC_; ++tl) {
        const int off = (tl >> 2) * 40 + (tl & 3);
        float s = 0.0f;
#pragma unroll
        for (int kk = 0; kk < 8; ++kk) s += cbase[kk * 1280 + off];
        const float cur2 = s + b2v;
        float m = fmaf(0.95f, mem2, cur2);
        m = m - spk2;
        mem2 = m;
        spk2 = (m > 1.0f) ? 1.0f : 0.0f;
        const int t = (ch - 1) * TC_ + tl;
        srec[(size_t)t * (B_ * NO_)] = spk2;
        mrec[(size_t)t * (B_ * NO_)] = m;
      }
    }

    // ---- (b) fused P2(ch) + P1(ch+1): 4 b-iters x {8 MFMA | 4 LIF steps} --
#pragma unroll
    for (int bi = 0; bi < 4; ++bi) {
      const int b = bset * 4 + bi;
      const int rbase = bbyte + ((b * TC_ + n15) * 65 + kc * 8) * 4 + g;
      f32x4 acc = {0.0f, 0.0f, 0.0f, 0.0f};
#pragma unroll
      for (int kbl = 0; kbl < 8; ++kbl) {
        const unsigned byt = bytes[rbase + kbl * 4];
        const uint2 lo2 = lut[byt & 15u];
        const uint2 hi2 = lut[byt >> 4];
        const u32x4 A = {lo2.x, lo2.y, hi2.x, hi2.y};
        const short8 af = __builtin_bit_cast(short8, A);
        acc = __builtin_amdgcn_mfma_f32_16x16x32_bf16(
            af, __builtin_bit_cast(short8, bhi[kbl]), acc, 0, 0, 0);
      }
      if (n15 < NO_)
        *reinterpret_cast<f32x4*>(
            &combC[((kc * 8 + b) * 4 + g) * 40 + n15 * 4]) = acc;
      if (ch < NCH - 1) {
        P1_STEP(bitsN16, 4 * bi);
        P1_STEP(bitsN16, 4 * bi + 1);
        P1_STEP(bitsN16, 4 * bi + 2);
        P1_STEP(bitsN16, 4 * bi + 3);
      }
    }

    __syncthreads();
    // fences: bits(nxt) ready for P2(ch+1); comb(cur) ready for P3/4(ch);
    // bits(cur) reads done before P1(ch+2) overwrites; comb(ch-1 parity)
    // reads done before P2(ch+1) overwrites.
  }

  // ---- epilogue: P3/4 for last chunk (parity (NCH-1)&1) ----
  if (w < 8 && lane < NO_) {
    const float* cbase = comb + ((NCH - 1) & 1) * COMB_PAR + w * 160 + lane * 4;
#pragma unroll
    for (int tl = 0; tl < TC_; ++tl) {
      const int off = (tl >> 2) * 40 + (tl & 3);
      float s = 0.0f;
#pragma unroll
      for (int kk = 0; kk < 8; ++kk) s += cbase[kk * 1280 + off];
      const float cur2 = s + b2v;
      float m = fmaf(0.95f, mem2, cur2);
      m = m - spk2;
      mem2 = m;
      spk2 = (m > 1.0f) ? 1.0f : 0.0f;
      const int t = (NCH - 1) * TC_ + tl;
      srec[(size_t)t * (B_ * NO_)] = spk2;
      mrec[(size_t)t * (B_ * NO_)] = m;
    }
  }
}

// ---------------------------------------------------------------------------
extern "C" void kernel_launch(void* const* d_in, const int* in_sizes, int n_in,
                              void* d_out, int out_size, void* d_ws, size_t ws_size,
                              hipStream_t stream) {
  const float* x  = (const float*)d_in[0];
  const float* w1 = (const float*)d_in[1];
  const float* b1 = (const float*)d_in[2];
  const float* w2 = (const float*)d_in[3];
  const float* b2 = (const float*)d_in[4];
  float* out = (float*)d_out;
  float* cur1 = (float*)d_ws;

  float* spk2_rec = out;
  float* mem2_rec = out + (size_t)T_ * B_ * NO_;

  (void)hipFuncSetAttribute(reinterpret_cast<const void*>(snn_loop),
                            hipFuncAttributeMaxDynamicSharedMemorySize,
                            SMEM_BYTES);

  dim3 g1(NH_ / 128, B_ / 128);
  gemm_cur1<<<g1, 512, 0, stream>>>(x, w1, b1, cur1);
  snn_loop<<<NBLK, 1024, SMEM_BYTES, stream>>>(cur1, w2, b2, spk2_rec, mem2_rec);
}

// Round 18
// 184.048 us; speedup vs baseline: 1.1502x; 1.0012x over previous
//
#include <hip/hip_runtime.h>
#include <hip/hip_bf16.h>

// SNN: B=2048, NI=1024, NH=2048, NO=10, T=128, BETA=0.95, THR=1.0
// K1: cur1 = x @ w1^T + b1 via bf16x3 MFMA (frozen).
// K2 r18 — r17 16-wave structure + amdgpu_waves_per_eu(4,4): dynamic LDS is
// invisible to the register allocator's occupancy heuristic, which targeted
// 8 waves/EU -> 64-VGPR cap -> spill (r17: WRITE 33.8MB vs 20.9MB outputs).
// Pinning 4 waves/EU gives a 128-VGPR budget that fits the ~110 live regs.

#define B_   2048
#define NI_  1024
#define NH_  2048
#define NO_  10
#define T_   128
#define GB_  8
#define NBLK (B_ / GB_)   // 256 blocks = 1/CU
#define TC_  16
#define NCH  (T_ / TC_)   // 8 chunks

typedef __attribute__((ext_vector_type(8))) short short8;
typedef __attribute__((ext_vector_type(4))) float f32x4;
typedef __attribute__((ext_vector_type(4))) unsigned int u32x4;

// bf16 round-to-nearest-even of an f32, low 16 bits.
__device__ __forceinline__ unsigned int bf16_rne(float f) {
  unsigned int u = __float_as_uint(f);
  return (u + 0x7FFFu + ((u >> 16) & 1u)) >> 16;
}

// ---------------- Kernel 1: cur1 = x @ w1^T + b1 (bf16x3 MFMA) --------------
#define G_ASTRIDE 144
#define G_AOFF    0
#define G_BOFF    (128 * G_ASTRIDE)
#define G_SMEM    (2 * 128 * G_ASTRIDE)

__global__ __launch_bounds__(512, 2) void gemm_cur1(
    const float* __restrict__ x, const float* __restrict__ w1,
    const float* __restrict__ b1, float* __restrict__ cur1) {
  __shared__ __align__(16) char smem[G_SMEM];
  const int tid = threadIdx.x;
  const int lane = tid & 63;
  const int wv = tid >> 6;
  const int wm = wv >> 2;
  const int wn = wv & 3;
  const int n15 = lane & 15;
  const int g = lane >> 4;
  const int brow = blockIdx.y * 128;
  const int bcol = blockIdx.x * 128;

  const int r_st = tid >> 3;
  const int kq = tid & 7;

  f32x4 acc[4][2];
#pragma unroll
  for (int tm = 0; tm < 4; ++tm)
#pragma unroll
    for (int tn = 0; tn < 2; ++tn) acc[tm][tn] = f32x4{0, 0, 0, 0};

  for (int kt = 0; kt < NI_; kt += 32) {
#pragma unroll
    for (int p = 0; p < 2; ++p) {
      const int r = r_st + p * 64;
      const float4 va = *reinterpret_cast<const float4*>(
          &x[(size_t)(brow + r) * NI_ + kt + kq * 4]);
      const float4 vb = *reinterpret_cast<const float4*>(
          &w1[(size_t)(bcol + r) * NI_ + kt + kq * 4]);
      const float fa[4] = {va.x, va.y, va.z, va.w};
      const float fb[4] = {vb.x, vb.y, vb.z, vb.w};
      unsigned ha[4], la[4], hb[4], lb[4];
#pragma unroll
      for (int c = 0; c < 4; ++c) {
        ha[c] = bf16_rne(fa[c]);
        la[c] = bf16_rne(fa[c] - __uint_as_float(ha[c] << 16));
        hb[c] = bf16_rne(fb[c]);
        lb[c] = bf16_rne(fb[c] - __uint_as_float(hb[c] << 16));
      }
      char* arow = smem + G_AOFF + r * G_ASTRIDE;
      char* brw  = smem + G_BOFF + r * G_ASTRIDE;
      *reinterpret_cast<uint2*>(arow + kq * 8) =
          uint2{ha[0] | (ha[1] << 16), ha[2] | (ha[3] << 16)};
      *reinterpret_cast<uint2*>(arow + 64 + kq * 8) =
          uint2{la[0] | (la[1] << 16), la[2] | (la[3] << 16)};
      *reinterpret_cast<uint2*>(brw + kq * 8) =
          uint2{hb[0] | (hb[1] << 16), hb[2] | (hb[3] << 16)};
      *reinterpret_cast<uint2*>(brw + 64 + kq * 8) =
          uint2{lb[0] | (lb[1] << 16), lb[2] | (lb[3] << 16)};
    }
    __syncthreads();

    short8 ah[4], al[4], bh2[2], bl2[2];
#pragma unroll
    for (int tm = 0; tm < 4; ++tm) {
      const char* p = smem + G_AOFF + (wm * 64 + tm * 16 + n15) * G_ASTRIDE;
      ah[tm] = *reinterpret_cast<const short8*>(p + g * 16);
      al[tm] = *reinterpret_cast<const short8*>(p + 64 + g * 16);
    }
#pragma unroll
    for (int tn = 0; tn < 2; ++tn) {
      const char* p = smem + G_BOFF + (wn * 32 + tn * 16 + n15) * G_ASTRIDE;
      bh2[tn] = *reinterpret_cast<const short8*>(p + g * 16);
      bl2[tn] = *reinterpret_cast<const short8*>(p + 64 + g * 16);
    }
#pragma unroll
    for (int tm = 0; tm < 4; ++tm)
#pragma unroll
      for (int tn = 0; tn < 2; ++tn) {
        acc[tm][tn] = __builtin_amdgcn_mfma_f32_16x16x32_bf16(
            ah[tm], bh2[tn], acc[tm][tn], 0, 0, 0);
        acc[tm][tn] = __builtin_amdgcn_mfma_f32_16x16x32_bf16(
            ah[tm], bl2[tn], acc[tm][tn], 0, 0, 0);
        acc[tm][tn] = __builtin_amdgcn_mfma_f32_16x16x32_bf16(
            al[tm], bh2[tn], acc[tm][tn], 0, 0, 0);
      }
    __syncthreads();
  }

#pragma unroll
  for (int tn = 0; tn < 2; ++tn) {
    const int col = bcol + wn * 32 + tn * 16 + n15;
    const float bias = b1[col];
#pragma unroll
    for (int tm = 0; tm < 4; ++tm) {
      const int rowb = brow + wm * 64 + tm * 16 + g * 4;
#pragma unroll
      for (int r = 0; r < 4; ++r)
        cur1[(size_t)(rowb + r) * NH_ + col] = acc[tm][tn][r] + bias;
    }
  }
}

// ---------------- Kernel 2: 16-wave pipelined LIF + time-as-M MFMA ----------
// Wave roles: P1: bq=w&7, hf=w>>3 (16 neurons/lane, h=hf*1024+lane*16+i).
//             P2: kc=w>>1 (K-chunk of 256), bset=w&1 (batches bset*4..+3).
//             P3/4: waves 0-7, batch w, lanes<10.
// LDS map (bytes):
//   lut  uint2[16]                      at 0       (128)
//   bits u32[2 par][8 b][16 tl][65]     at 128     (2 x 33280)
//   comb f32[2 par][8 kc][8 b][4 g][40] at 66688   (2 x 40960)
#define LUT_OFF  0
#define BITS_OFF 128
#define BITS_PAR 8320    // words per parity
#define COMB_OFF 66688
#define COMB_PAR 10240   // floats per parity
#define SMEM_BYTES 148608

__global__
__attribute__((amdgpu_flat_work_group_size(1024, 1024)))
__attribute__((amdgpu_waves_per_eu(4, 4)))
void snn_loop(
    const float* __restrict__ cur1, const float* __restrict__ w2,
    const float* __restrict__ b2, float* __restrict__ spk2_rec,
    float* __restrict__ mem2_rec) {
  extern __shared__ char smem[];
  uint2* lutw = reinterpret_cast<uint2*>(smem + LUT_OFF);
  const uint2* lut = lutw;
  float* comb = reinterpret_cast<float*>(smem + COMB_OFF);
  const int tid = threadIdx.x;
  const int lane = tid & 63;
  const int w = tid >> 6;               // wave 0..15
  const int bq = w & 7;                 // P1: local batch
  const int hf = w >> 3;                // P1: neuron half
  const int kc = w >> 1;                // P2: K-chunk (0..7)
  const int bset = w & 1;               // P2: batch set (4 batches)
  const int bbase = blockIdx.x * GB_;

  if (tid < 16) {
    lutw[tid] = uint2{(tid & 1 ? 0x3F80u : 0u) | (tid & 2 ? 0x3F800000u : 0u),
                      (tid & 4 ? 0x3F80u : 0u) | (tid & 8 ? 0x3F800000u : 0u)};
  }

  // ---- P1 state: 16 neurons/lane, 4-inst cc-form (64 regs) ----
  float mem1[16], c1v[16], c1m[16], cc[16];
  {
    const float* base = cur1 + (size_t)(bbase + bq) * NH_ + hf * 1024 + lane * 16;
#pragma unroll
    for (int q = 0; q < 4; ++q) {
      const float4 v = *reinterpret_cast<const float4*>(base + q * 4);
      c1v[q * 4 + 0] = v.x; c1v[q * 4 + 1] = v.y;
      c1v[q * 4 + 2] = v.z; c1v[q * 4 + 3] = v.w;
    }
#pragma unroll
    for (int i = 0; i < 16; ++i) {
      mem1[i] = 0.0f;
      c1m[i] = c1v[i] - 1.0f;
      cc[i] = c1v[i];
    }
  }

  // ---- P2: w2 B-fragments, single bf16 (32 regs); kb = kc*8 + kbl ----
  u32x4 bhi[8];
  {
    const int o = lane & 15;
    const int koff = (lane >> 4) * 8;
#pragma unroll
    for (int kbl = 0; kbl < 8; ++kbl) {
      const int kb = kc * 8 + kbl;
      unsigned int hw[4];
#pragma unroll
      for (int p = 0; p < 4; ++p) {
        unsigned int h0 = 0, h1 = 0;
        if (o < NO_) {
          const int k = kb * 32 + koff + p * 2;
          h0 = bf16_rne(w2[(size_t)o * NH_ + k]);
          h1 = bf16_rne(w2[(size_t)o * NH_ + k + 1]);
        }
        hw[p] = h0 | (h1 << 16);
      }
      bhi[kbl] = u32x4{hw[0], hw[1], hw[2], hw[3]};
    }
  }

  // ---- layer-2 state: waves 0-7, lanes < NO_ own (batch w, output lane) ----
  float mem2 = 0.0f, spk2 = 0.0f, b2v = 0.0f;
  float *srec = nullptr, *mrec = nullptr;
  if (w < 8 && lane < NO_) {
    b2v = b2[lane];
    srec = spk2_rec + (size_t)(bbase + w) * NO_ + lane;
    mrec = mem2_rec + (size_t)(bbase + w) * NO_ + lane;
  }

  const int n15 = lane & 15;
  const int g = lane >> 4;
  const unsigned char* bytes = reinterpret_cast<const unsigned char*>(smem);

  // P1 halfword slot: word (bq*TC+tl)*65 + hf*32 + (lane>>1), half lane&1
  const int bits_hw = (hf * 32 + (lane >> 1)) * 2 + (lane & 1);

  auto P1_STEP = [&](unsigned short* bitsP16, int tl) {
    unsigned W = 0;
#pragma unroll
    for (int i = 15; i >= 0; --i) {
      const float m = fmaf(0.95f, mem1[i], cc[i]);
      mem1[i] = m;
      const bool c = m > 1.0f;
      W = W + W + (c ? 1u : 0u);
      cc[i] = c ? c1m[i] : c1v[i];
    }
    bitsP16[(bq * TC_ + tl) * 130 + bits_hw] = (unsigned short)W;
  };

  // ---- prologue: P1(chunk 0) -> parity 0 ----
  {
    unsigned short* b16 = reinterpret_cast<unsigned short*>(smem + BITS_OFF);
    for (int tl = 0; tl < TC_; ++tl) P1_STEP(b16, tl);
  }
  __syncthreads();

  for (int ch = 0; ch < NCH; ++ch) {
    const int cur = ch & 1;
    unsigned short* bitsN16 = reinterpret_cast<unsigned short*>(
        smem + BITS_OFF + (cur ^ 1) * (BITS_PAR * 4));
    float* combC = comb + cur * COMB_PAR;
    const float* combV = comb + (cur ^ 1) * COMB_PAR;  // parity of ch-1
    const int bbyte = BITS_OFF + cur * (BITS_PAR * 4);

    // ---- (a) P3/4 for chunk ch-1 (waves 0-7) ----
    if (ch > 0 && w < 8 && lane < NO_) {
      const float* cbase = combV + w * 160 + lane * 4;
#pragma unroll
      for (int tl = 0; tl < TC_; ++tl) {
        const int off = (tl >> 2) * 40 + (tl & 3);
        float s = 0.0f;
#pragma unroll
        for (int kk = 0; kk < 8; ++kk) s += cbase[kk * 1280 + off];
        const float cur2 = s + b2v;
        float m = fmaf(0.95f, mem2, cur2);
        m = m - spk2;
        mem2 = m;
        spk2 = (m > 1.0f) ? 1.0f : 0.0f;
        const int t = (ch - 1) * TC_ + tl;
        srec[(size_t)t * (B_ * NO_)] = spk2;
        mrec[(size_t)t * (B_ * NO_)] = m;
      }
    }

    // ---- (b) fused P2(ch) + P1(ch+1): 4 b-iters x {8 MFMA | 4 LIF steps} --
#pragma unroll
    for (int bi = 0; bi < 4; ++bi) {
      const int b = bset * 4 + bi;
      const int rbase = bbyte + ((b * TC_ + n15) * 65 + kc * 8) * 4 + g;
      f32x4 acc = {0.0f, 0.0f, 0.0f, 0.0f};
#pragma unroll
      for (int kbl = 0; kbl < 8; ++kbl) {
        const unsigned byt = bytes[rbase + kbl * 4];
        const uint2 lo2 = lut[byt & 15u];
        const uint2 hi2 = lut[byt >> 4];
        const u32x4 A = {lo2.x, lo2.y, hi2.x, hi2.y};
        const short8 af = __builtin_bit_cast(short8, A);
        acc = __builtin_amdgcn_mfma_f32_16x16x32_bf16(
            af, __builtin_bit_cast(short8, bhi[kbl]), acc, 0, 0, 0);
      }
      if (n15 < NO_)
        *reinterpret_cast<f32x4*>(
            &combC[((kc * 8 + b) * 4 + g) * 40 + n15 * 4]) = acc;
      if (ch < NCH - 1) {
        P1_STEP(bitsN16, 4 * bi);
        P1_STEP(bitsN16, 4 * bi + 1);
        P1_STEP(bitsN16, 4 * bi + 2);
        P1_STEP(bitsN16, 4 * bi + 3);
      }
    }

    __syncthreads();
    // fences: bits(nxt) ready for P2(ch+1); comb(cur) ready for P3/4(ch);
    // bits(cur) reads done before P1(ch+2) overwrites; comb(ch-1 parity)
    // reads done before P2(ch+1) overwrites.
  }

  // ---- epilogue: P3/4 for last chunk (parity (NCH-1)&1) ----
  if (w < 8 && lane < NO_) {
    const float* cbase = comb + ((NCH - 1) & 1) * COMB_PAR + w * 160 + lane * 4;
#pragma unroll
    for (int tl = 0; tl < TC_; ++tl) {
      const int off = (tl >> 2) * 40 + (tl & 3);
      float s = 0.0f;
#pragma unroll
      for (int kk = 0; kk < 8; ++kk) s += cbase[kk * 1280 + off];
      const float cur2 = s + b2v;
      float m = fmaf(0.95f, mem2, cur2);
      m = m - spk2;
      mem2 = m;
      spk2 = (m > 1.0f) ? 1.0f : 0.0f;
      const int t = (NCH - 1) * TC_ + tl;
      srec[(size_t)t * (B_ * NO_)] = spk2;
      mrec[(size_t)t * (B_ * NO_)] = m;
    }
  }
}

// ---------------------------------------------------------------------------
extern "C" void kernel_launch(void* const* d_in, const int* in_sizes, int n_in,
                              void* d_out, int out_size, void* d_ws, size_t ws_size,
                              hipStream_t stream) {
  const float* x  = (const float*)d_in[0];
  const float* w1 = (const float*)d_in[1];
  const float* b1 = (const float*)d_in[2];
  const float* w2 = (const float*)d_in[3];
  const float* b2 = (const float*)d_in[4];
  float* out = (float*)d_out;
  float* cur1 = (float*)d_ws;

  float* spk2_rec = out;
  float* mem2_rec = out + (size_t)T_ * B_ * NO_;

  (void)hipFuncSetAttribute(reinterpret_cast<const void*>(snn_loop),
                            hipFuncAttributeMaxDynamicSharedMemorySize,
                            SMEM_BYTES);

  dim3 g1(NH_ / 128, B_ / 128);
  gemm_cur1<<<g1, 512, 0, stream>>>(x, w1, b1, cur1);
  snn_loop<<<NBLK, 1024, SMEM_BYTES, stream>>>(cur1, w2, b2, spk2_rec, mem2_rec);
}